// Round 3
// baseline (157.708 us; speedup 1.0000x reference)
//
#include <hip/hip_runtime.h>
#include <hip/hip_bf16.h>

#define DIN 64
#define DOUT 62
#define ICH 32
#define OCH 64

typedef __bf16 bf16x8 __attribute__((ext_vector_type(8)));
typedef float f32x4 __attribute__((ext_vector_type(4)));

// ---------- prep: W[oc][ic][kz][ky][kx] f32 -> Wre[tap][oc][ic] bf16(ushort) ----------
__global__ void prep_w(const float* __restrict__ W, unsigned short* __restrict__ Wre) {
    int idx = blockIdx.x * 256 + threadIdx.x;        // 27*64*32 = 55296
    if (idx >= 27 * OCH * ICH) return;
    int ic  = idx & 31;
    int oc  = (idx >> 5) & 63;
    int tap = idx >> 11;
    float v = W[((size_t)oc * ICH + ic) * 27 + tap];
    Wre[idx] = __builtin_bit_cast(unsigned short, (__bf16)v);
}

// ---------- main: implicit GEMM, kz-outer, one z-plane in LDS (25.3 KB) ----------
// block tile: (b, d, 4 h-rows) x 64 oc x 64 w.  wave = one h row.
// LDS x-plane: [y(6)][w(66)][4 slots of 16B(8 ic bf16)], slot = icg ^ ((w>>1)&3)
template<bool USE_WRE>
__global__ __launch_bounds__(256, 4) void conv3d_mfma(
    const float* __restrict__ x, const float* __restrict__ W,
    const unsigned short* __restrict__ Wre, float* __restrict__ out)
{
    __shared__ int4 xs4[6 * 66 * 4];                 // 25,344 B
    char* xs = (char*)xs4;

    const int tid  = threadIdx.x;
    const int lane = tid & 63;
    const int wave = tid >> 6;

    int bid = blockIdx.x;
    const int ht = bid & 15; bid >>= 4;
    const int d  = bid % DOUT;
    const int b  = bid / DOUT;
    const int h0 = ht * 4;

    const int wlo = lane & 15;                       // w-in-tile / oc-in-tile
    const int whi = lane >> 4;                       // k-group (8 ic)
    const int row = wave;                            // h row

    f32x4 acc[4][4];                                 // [mt=oc-tile][nt=w-tile]
#pragma unroll
    for (int mt = 0; mt < 4; ++mt)
#pragma unroll
        for (int nt = 0; nt < 4; ++nt)
            acc[mt][nt] = f32x4{0.f, 0.f, 0.f, 0.f};

    for (int kz = 0; kz < 3; ++kz) {
        __syncthreads();                             // protect previous plane's readers
        // ---- stage plane z = d+kz: thread (wave=icg, lane=w) packs 8 ic -> b128 per y ----
        {
            const int icg  = wave;
            const int w    = lane;
            const int slot = icg ^ ((w >> 1) & 3);
#pragma unroll
            for (int y = 0; y < 6; ++y) {
                int gy = h0 + y; if (gy > 63) gy = 63;   // clamped rows feed only discarded h
                const float* xp = x + (((size_t)(b * ICH + icg * 8) * DIN + (d + kz)) * DIN + gy) * DIN + w;
                bf16x8 pk;
#pragma unroll
                for (int j = 0; j < 8; ++j)
                    pk[j] = (__bf16)xp[(size_t)j * DIN * DIN * DIN];
                *(int4*)(xs + ((y * 66 + w) * 64 + slot * 16)) = __builtin_bit_cast(int4, pk);
            }
            if (tid < 48) {                          // zero w = 64,65 (all 4 slots)
                int y = tid >> 3, q = tid & 7;
                int w2 = 64 + (q >> 2), sl = q & 3;
                *(int4*)(xs + ((y * 66 + w2) * 64 + sl * 16)) = int4{0, 0, 0, 0};
            }
        }
        __syncthreads();

        // ---- 9 taps of this kz, software-pipelined A (W) fragments ----
        bf16x8 af[2][4];
        // prologue: load A for tap (ky=0,kx=0)
        {
            const int tap = kz * 9;
            if (USE_WRE) {
                const char* wp = (const char*)Wre + (size_t)tap * (OCH * ICH * 2) + whi * 16;
#pragma unroll
                for (int mt = 0; mt < 4; ++mt)
                    af[0][mt] = __builtin_bit_cast(bf16x8, *(const int4*)(wp + (mt * 16 + wlo) * 64));
            } else {
#pragma unroll
                for (int mt = 0; mt < 4; ++mt) {
                    const float* wp = W + ((size_t)(mt * 16 + wlo) * ICH + whi * 8) * 27 + tap;
                    bf16x8 t;
#pragma unroll
                    for (int j = 0; j < 8; ++j) t[j] = (__bf16)wp[j * 27];
                    af[0][mt] = t;
                }
            }
        }

#pragma unroll
        for (int t = 0; t < 9; ++t) {
            const int ky = t / 3, kx = t % 3;
            // prefetch next tap's A fragments into the other buffer
            if (t < 8) {
                const int tap = kz * 9 + t + 1;
                if (USE_WRE) {
                    const char* wp = (const char*)Wre + (size_t)tap * (OCH * ICH * 2) + whi * 16;
#pragma unroll
                    for (int mt = 0; mt < 4; ++mt)
                        af[(t + 1) & 1][mt] = __builtin_bit_cast(bf16x8, *(const int4*)(wp + (mt * 16 + wlo) * 64));
                } else {
#pragma unroll
                    for (int mt = 0; mt < 4; ++mt) {
                        const float* wp = W + ((size_t)(mt * 16 + wlo) * ICH + whi * 8) * 27 + tap;
                        bf16x8 tv;
#pragma unroll
                        for (int j = 0; j < 8; ++j) tv[j] = (__bf16)wp[j * 27];
                        af[(t + 1) & 1][mt] = tv;
                    }
                }
            }
            // B fragments from LDS (one ds_read_b128 each)
            bf16x8 bfr[4];
#pragma unroll
            for (int nt = 0; nt < 4; ++nt) {
                int w = nt * 16 + wlo + kx;
                int slot = whi ^ ((w >> 1) & 3);
                bfr[nt] = __builtin_bit_cast(bf16x8,
                    *(const int4*)(xs + (((row + ky) * 66 + w) * 64 + slot * 16)));
            }
#pragma unroll
            for (int mt = 0; mt < 4; ++mt)
#pragma unroll
                for (int nt = 0; nt < 4; ++nt)
                    acc[mt][nt] = __builtin_amdgcn_mfma_f32_16x16x32_bf16(
                        af[t & 1][mt], bfr[nt], acc[mt][nt], 0, 0, 0);
        }
    }

    // ---- store: D row=(l>>4)*4+r -> oc, col=l&15 -> w ----
    const int h = h0 + row;
    if (h < DOUT) {
#pragma unroll
        for (int mt = 0; mt < 4; ++mt) {
#pragma unroll
            for (int r = 0; r < 4; ++r) {
                int oc = mt * 16 + whi * 4 + r;
                size_t ob = ((((size_t)b * OCH + oc) * DOUT + d) * DOUT + h) * DOUT;
#pragma unroll
                for (int nt = 0; nt < 4; ++nt) {
                    int w = nt * 16 + wlo;
                    if (w < DOUT) out[ob + w] = acc[mt][nt][r];
                }
            }
        }
    }
}

extern "C" void kernel_launch(void* const* d_in, const int* in_sizes, int n_in,
                              void* d_out, int out_size, void* d_ws, size_t ws_size,
                              hipStream_t stream) {
    const float* x = (const float*)d_in[0];
    const float* W = (const float*)d_in[1];
    float* out = (float*)d_out;

    const dim3 grid(2 * DOUT * 16);                  // b * d * h-tiles = 1984
    const size_t wre_bytes = (size_t)27 * OCH * ICH * 2;

    if (ws_size >= wre_bytes) {
        unsigned short* Wre = (unsigned short*)d_ws;
        prep_w<<<dim3((27 * OCH * ICH + 255) / 256), 256, 0, stream>>>(W, Wre);
        conv3d_mfma<true><<<grid, 256, 0, stream>>>(x, W, Wre, out);
    } else {
        conv3d_mfma<false><<<grid, 256, 0, stream>>>(x, W, nullptr, out);
    }
}

// Round 4
// 137.914 us; speedup vs baseline: 1.1435x; 1.1435x over previous
//
#include <hip/hip_runtime.h>
#include <hip/hip_bf16.h>

#define DIN 64
#define DOUT 62
#define ICH 32
#define OCH 64

typedef __bf16 bf16x8 __attribute__((ext_vector_type(8)));
typedef float f32x4 __attribute__((ext_vector_type(4)));

// ---------- prep: W[oc][ic][kz][ky][kx] f32 -> Wre[tap][oc][ic] bf16(ushort) ----------
__global__ void prep_w(const float* __restrict__ W, unsigned short* __restrict__ Wre) {
    int idx = blockIdx.x * 256 + threadIdx.x;        // 27*64*32 = 55296
    if (idx >= 27 * OCH * ICH) return;
    int ic  = idx & 31;
    int oc  = (idx >> 5) & 63;
    int tap = idx >> 11;
    float v = W[((size_t)oc * ICH + ic) * 27 + tap];
    Wre[idx] = __builtin_bit_cast(unsigned short, (__bf16)v);
}

// ---------- main: implicit GEMM, kz-outer, rolling 2-plane LDS dbuf (50.7 KB) ----------
// block tile: (b, d, 4 h-rows) x 64 oc x 64 w.  wave = one h row.
// LDS plane: [y(6)][w(66)][4 slots of 16B(8 ic bf16)], slot = icg ^ ((w>>1)&3)
// XCD swizzle: 1984 blocks = 8 XCDs x 248; each XCD walks a contiguous (b,d,ht) chunk.
template<bool USE_WRE>
__global__ __launch_bounds__(256, 3) void conv3d_mfma(
    const float* __restrict__ x, const float* __restrict__ W,
    const unsigned short* __restrict__ Wre, float* __restrict__ out)
{
    __shared__ char xs[2][6 * 66 * 64];              // 2 x 25,344 B

    const int tid  = threadIdx.x;
    const int lane = tid & 63;
    const int wave = tid >> 6;

    // bijective XCD-aware swizzle (nwg = 1984 = 8*248 exactly)
    const int orig = blockIdx.x;
    const int lid  = (orig & 7) * 248 + (orig >> 3);
    const int ht = lid & 15;
    const int rr = lid >> 4;                         // 0..123
    const int d  = rr % DOUT;
    const int b  = rr / DOUT;
    const int h0 = ht * 4;

    const int wlo = lane & 15;                       // w-in-tile / oc-in-tile
    const int whi = lane >> 4;                       // k-group (8 ic)
    const int row = wave;                            // h row

    // staging role: thread (wave=icg, lane=w)
    const int icg  = wave;
    const int w    = lane;
    const int slot = icg ^ ((w >> 1) & 3);

    auto issue2 = [&](int z, int y0, float* s) {     // issue 16 global f32 loads (2 y-rows)
#pragma unroll
        for (int yy = 0; yy < 2; ++yy) {
            int gy = h0 + y0 + yy; if (gy > 63) gy = 63;   // clamped rows feed only discarded h
#pragma unroll
            for (int j = 0; j < 8; ++j)
                s[yy * 8 + j] =
                    x[(((size_t)(b * ICH + icg * 8 + j) * DIN + z) * DIN + gy) * DIN + w];
        }
    };
    auto write2 = [&](char* buf, int y0, const float* s) {   // cvt + 2 ds_write_b128
#pragma unroll
        for (int yy = 0; yy < 2; ++yy) {
            bf16x8 pk;
#pragma unroll
            for (int j = 0; j < 8; ++j) pk[j] = (__bf16)s[yy * 8 + j];
            *(int4*)(buf + (((y0 + yy) * 66 + w) * 64 + slot * 16)) = __builtin_bit_cast(int4, pk);
        }
    };
    auto loadA = [&](int tap, int4* af) {
        if (USE_WRE) {
            const char* wp = (const char*)Wre + (size_t)tap * (OCH * ICH * 2) + whi * 16;
#pragma unroll
            for (int mt = 0; mt < 4; ++mt)
                af[mt] = *(const int4*)(wp + (mt * 16 + wlo) * 64);
        } else {
#pragma unroll
            for (int mt = 0; mt < 4; ++mt) {
                const float* wp = W + ((size_t)(mt * 16 + wlo) * ICH + whi * 8) * 27 + tap;
                bf16x8 t;
#pragma unroll
                for (int j = 0; j < 8; ++j) t[j] = (__bf16)wp[j * 27];
                af[mt] = __builtin_bit_cast(int4, t);
            }
        }
    };

    // zero the w=64,65 pad columns of BOTH buffers once (never overwritten later)
    if (tid < 96) {
        int bu = tid / 48, q2 = tid % 48;
        int y = q2 >> 3, q = q2 & 7;
        int w2 = 64 + (q >> 2), sl = q & 3;
        *(int4*)(xs[bu] + ((y * 66 + w2) * 64 + sl * 16)) = int4{0, 0, 0, 0};
    }

    // prologue: stage plane d into buf0 (issue all, then write all — one latency exposure)
    {
        float s0[16], s1[16], s2[16];
        issue2(d, 0, s0); issue2(d, 2, s1); issue2(d, 4, s2);
        write2(xs[0], 0, s0); write2(xs[0], 2, s1); write2(xs[0], 4, s2);
    }
    int4 af[2][4];
    loadA(0, af[0]);
    __syncthreads();

    f32x4 acc[4][4];
#pragma unroll
    for (int mt = 0; mt < 4; ++mt)
#pragma unroll
        for (int nt = 0; nt < 4; ++nt)
            acc[mt][nt] = f32x4{0.f, 0.f, 0.f, 0.f};

#pragma unroll                                        // kz compile-time -> all indices static
    for (int kz = 0; kz < 3; ++kz) {
        char* cur = xs[kz & 1];
        char* nxt = xs[(kz + 1) & 1];
        float s0[16], s1[16], s2[16];
        if (kz < 2) issue2(d + kz + 1, 0, s0);        // batch0 in flight under taps 0..2

#pragma unroll
        for (int t = 0; t < 9; ++t) {
            const int T  = kz * 9 + t;               // global tap index (parity continuous)
            const int ky = t / 3, kx = t % 3;
            if (T < 26) loadA(T + 1, af[(T + 1) & 1]);   // 1-deep A prefetch

            bf16x8 bfr[4];
#pragma unroll
            for (int nt = 0; nt < 4; ++nt) {
                int wb = nt * 16 + wlo + kx;
                int sl = whi ^ ((wb >> 1) & 3);
                bfr[nt] = __builtin_bit_cast(bf16x8,
                    *(const int4*)(cur + (((row + ky) * 66 + wb) * 64 + sl * 16)));
            }
#pragma unroll
            for (int mt = 0; mt < 4; ++mt)
#pragma unroll
                for (int nt = 0; nt < 4; ++nt)
                    acc[mt][nt] = __builtin_amdgcn_mfma_f32_16x16x32_bf16(
                        __builtin_bit_cast(bf16x8, af[T & 1][mt]), bfr[nt], acc[mt][nt], 0, 0, 0);

            // async-STAGE split: write batch after ~3 taps of MFMA covered its latency
            if (kz < 2) {
                if (t == 2) { write2(nxt, 0, s0); issue2(d + kz + 1, 2, s1); }
                if (t == 5) { write2(nxt, 2, s1); issue2(d + kz + 1, 4, s2); }
                if (t == 8) { write2(nxt, 4, s2); }
            }
        }
        if (kz < 2) __syncthreads();                  // next plane ready; one barrier/segment
    }

    // ---- store: D row=(l>>4)*4+r -> oc, col=l&15 -> w ----
    const int h = h0 + row;
    if (h < DOUT) {
#pragma unroll
        for (int mt = 0; mt < 4; ++mt) {
#pragma unroll
            for (int r = 0; r < 4; ++r) {
                int oc = mt * 16 + whi * 4 + r;
                size_t ob = ((((size_t)b * OCH + oc) * DOUT + d) * DOUT + h) * DOUT;
#pragma unroll
                for (int nt = 0; nt < 4; ++nt) {
                    int ww = nt * 16 + wlo;
                    if (ww < DOUT) out[ob + ww] = acc[mt][nt][r];
                }
            }
        }
    }
}

extern "C" void kernel_launch(void* const* d_in, const int* in_sizes, int n_in,
                              void* d_out, int out_size, void* d_ws, size_t ws_size,
                              hipStream_t stream) {
    const float* x = (const float*)d_in[0];
    const float* W = (const float*)d_in[1];
    float* out = (float*)d_out;

    const dim3 grid(2 * DOUT * 16);                  // 1984 blocks = 8 XCDs * 248
    const size_t wre_bytes = (size_t)27 * OCH * ICH * 2;

    if (ws_size >= wre_bytes) {
        unsigned short* Wre = (unsigned short*)d_ws;
        prep_w<<<dim3((27 * OCH * ICH + 255) / 256), 256, 0, stream>>>(W, Wre);
        conv3d_mfma<true><<<grid, 256, 0, stream>>>(x, W, Wre, out);
    } else {
        conv3d_mfma<false><<<grid, 256, 0, stream>>>(x, W, nullptr, out);
    }
}